// Round 3
// baseline (635.104 us; speedup 1.0000x reference)
//
#include <hip/hip_runtime.h>
#include <stdint.h>

#define NN 50000
#define EE 800000
#define INF_ 256
#define OUTF 32
#define HH 8
#define NEG_SLOPE 0.2f
#define EPS_ 1e-8f

// ---------------- p-vectors: p[h,i] = sum_f W[h,i,f] * a[h,f] ----------------
__global__ void k_pvec(const float* __restrict__ W, const float* __restrict__ a_src,
                       const float* __restrict__ a_dst, float* __restrict__ p_src,
                       float* __restrict__ p_dst){
  int idx = blockIdx.x*blockDim.x + threadIdx.x;   // h*256 + i
  if (idx >= HH*INF_) return;
  int h = idx >> 8;
  const float* w = W + idx*OUTF;
  float ps = 0.f, pd = 0.f;
#pragma unroll
  for (int f = 0; f < OUTF; ++f){
    float wv = w[f];
    ps += wv * a_src[h*OUTF + f];
    pd += wv * a_dst[h*OUTF + f];
  }
  p_src[idx] = ps; p_dst[idx] = pd;
}

// ---------------- GEMM: h_f[n, h*32+f] = sum_i x[n,i] W[h,i,f]  (all fp32) ----------------
#define TM 128
#define TN 128
#define TK 32
#define LS 132   // padded LDS row stride (floats, multiple of 4 for float4 access)

__global__ __launch_bounds__(256) void k_gemm(const float* __restrict__ x,
                                              const float* __restrict__ W,
                                              float* __restrict__ h_out){
  __shared__ float As[TK*LS];
  __shared__ float Bs[TK*LS];
  int tid = threadIdx.x;
  int bx = blockIdx.x & 1;         // col tile (cols 0..127 / 128..255)
  int by = blockIdx.x >> 1;        // row tile
  int n0 = by*TM, c0 = bx*TN;
  int tx = tid & 15, ty = tid >> 4;
  float acc[8][8];
#pragma unroll
  for (int i=0;i<8;i++)
#pragma unroll
    for (int j=0;j<8;j++) acc[i][j]=0.f;

  // A staging: thread loads float4 of x; a_kg = k-group of 4, a_nd = node base
  int a_kg = tid & 7;        // k4-group: k = a_kg*4 .. +3
  int a_nd = tid >> 3;       // node 0..31 (+s*32)
  // B staging: b_fg = f4-group, b_h = head-local, b_kk = k base
  int b_fg = tid & 7;        // f = b_fg*4 (0..28)
  int b_h  = (tid >> 3) & 3; // head-local 0..3
  int b_kk = tid >> 5;       // kk 0..7 (+s*8)
  int h0 = c0 >> 5;          // base head

  for (int k0 = 0; k0 < INF_; k0 += TK){
#pragma unroll
    for (int s = 0; s < 4; ++s){
      int node = a_nd + s*32;
      int n = n0 + node;
      float4 u = make_float4(0.f,0.f,0.f,0.f);
      if (n < NN) u = *(const float4*)(x + n*INF_ + k0 + a_kg*4);
      int kb = a_kg*4;
      As[(kb+0)*LS + node] = u.x;
      As[(kb+1)*LS + node] = u.y;
      As[(kb+2)*LS + node] = u.z;
      As[(kb+3)*LS + node] = u.w;
    }
#pragma unroll
    for (int s = 0; s < 4; ++s){
      int kk = b_kk + s*8;
      float4 u = *(const float4*)(W + (h0 + b_h)*(INF_*OUTF) + (k0 + kk)*OUTF + b_fg*4);
      *(float4*)&Bs[kk*LS + b_h*32 + b_fg*4] = u;
    }
    __syncthreads();
#pragma unroll 8
    for (int kk = 0; kk < TK; ++kk){
      float4 A0 = *(const float4*)&As[kk*LS + ty*4];
      float4 A1 = *(const float4*)&As[kk*LS + 64 + ty*4];
      float4 B0 = *(const float4*)&Bs[kk*LS + tx*4];
      float4 B1 = *(const float4*)&Bs[kk*LS + 64 + tx*4];
      float av[8] = {A0.x,A0.y,A0.z,A0.w,A1.x,A1.y,A1.z,A1.w};
      float bv[8] = {B0.x,B0.y,B0.z,B0.w,B1.x,B1.y,B1.z,B1.w};
#pragma unroll
      for (int r=0;r<8;r++)
#pragma unroll
        for (int c=0;c<8;c++)
          acc[r][c] += av[r]*bv[c];
    }
    __syncthreads();
  }
#pragma unroll
  for (int r=0;r<8;r++){
    int node = (r<4) ? (ty*4 + r) : (64 + ty*4 + (r-4));
    int n = n0 + node;
    if (n >= NN) continue;
    float4 o0 = make_float4(acc[r][0], acc[r][1], acc[r][2], acc[r][3]);
    float4 o1 = make_float4(acc[r][4], acc[r][5], acc[r][6], acc[r][7]);
    *(float4*)(h_out + n*INF_ + c0 + tx*4)      = o0;
    *(float4*)(h_out + n*INF_ + c0 + 64 + tx*4) = o1;
  }
}

// ---------------- scores: s_src[n,h] = x[n]·p_src[h], s_dst likewise (LDS-free) ----------------
__global__ __launch_bounds__(256) void k_scores(const float* __restrict__ x,
    const float* __restrict__ p_src, const float* __restrict__ p_dst,
    float* __restrict__ s_src, float* __restrict__ s_dst){
  int tid = threadIdx.x;
  int n = blockIdx.x*16 + (tid >> 4);
  if (n >= NN) return;
  int slot = tid & 15;
  int h = slot & 7, isdst = slot >> 3;
  const float4* p4 = (const float4*)((isdst ? p_dst : p_src) + h*INF_);
  const float4* x4 = (const float4*)(x + n*INF_);
  float s = 0.f;
#pragma unroll 8
  for (int i = 0; i < 64; ++i){
    float4 a = x4[i], b = p4[i];
    s += a.x*b.x + a.y*b.y + a.z*b.z + a.w*b.w;
  }
  (isdst ? s_dst : s_src)[n*8 + h] = s;
}

// ---------------- CSR build ----------------
__global__ void k_hist(const int* __restrict__ ei, int* __restrict__ count){
  int e = blockIdx.x*blockDim.x + threadIdx.x;
  if (e < EE) atomicAdd(&count[ei[EE + e]], 1);
}

__global__ void k_scan(const int* __restrict__ count, int* __restrict__ row_ptr,
                       int* __restrict__ w_off){
  __shared__ int lds[1024];
  int t = threadIdx.x;
  const int CH = 49;               // 1024*49 >= 50000
  int base = t*CH;
  int lsum = 0;
  for (int i=0;i<CH;i++){ int idx = base+i; if (idx < NN) lsum += count[idx]; }
  lds[t] = lsum;
  __syncthreads();
  for (int off=1; off<1024; off<<=1){
    int add = (t >= off) ? lds[t-off] : 0;
    __syncthreads();
    lds[t] += add;
    __syncthreads();
  }
  int excl = lds[t] - lsum;        // exclusive prefix
  for (int i=0;i<CH;i++){
    int idx = base+i;
    if (idx < NN){ row_ptr[idx] = excl; w_off[idx] = excl; excl += count[idx]; }
  }
  if (t == 1023) row_ptr[NN] = lds[1023];
}

__global__ void k_scatter(const int* __restrict__ ei, int* __restrict__ w_off,
                          int* __restrict__ csr){
  int e = blockIdx.x*blockDim.x + threadIdx.x;
  if (e < EE){
    int d = ei[EE + e];
    int pos = atomicAdd(&w_off[d], 1);
    csr[pos] = ei[e];              // src node id
  }
}

// ---------------- fused online-softmax aggregation: one wave per dst node ----------------
__global__ __launch_bounds__(256) void k_agg(const int* __restrict__ row_ptr,
    const int* __restrict__ csr, const float* __restrict__ s_src,
    const float* __restrict__ s_dst, const float* __restrict__ h_f,
    float* __restrict__ out){
  int lane = threadIdx.x & 63;
  int n = blockIdx.x*4 + (threadIdx.x >> 6);
  if (n >= NN) return;
  int h = lane >> 3, q = lane & 7;          // lane owns head h, f in [q*4, q*4+4)
  float sd = s_dst[n*8 + h];
  int beg = row_ptr[n], end = row_ptr[n+1];
  float m = -1e30f, l = 0.f;
  float a0=0.f, a1=0.f, a2=0.f, a3=0.f;
  for (int j = beg; j < end; ++j){
    int src = csr[j];
    float sc = s_src[src*8 + h] + sd;
    sc = sc > 0.f ? sc : NEG_SLOPE*sc;      // LeakyReLU
    float mn = fmaxf(m, sc);
    float scale = __expf(m - mn);           // exp(-huge)=0 handles first edge
    float p = __expf(sc - mn);
    m = mn;
    l = l*scale + p;
    float4 hv = *(const float4*)(h_f + src*INF_ + h*32 + q*4);
    a0 = a0*scale + p*hv.x;
    a1 = a1*scale + p*hv.y;
    a2 = a2*scale + p*hv.z;
    a3 = a3*scale + p*hv.w;
  }
  float inv = 1.f/(l + EPS_);
  float4 o = make_float4(a0*inv, a1*inv, a2*inv, a3*inv);
  *(float4*)(out + n*INF_ + h*32 + q*4) = o;
}

// ---------------- launch ----------------
extern "C" void kernel_launch(void* const* d_in, const int* in_sizes, int n_in,
                              void* d_out, int out_size, void* d_ws, size_t ws_size,
                              hipStream_t stream){
  const float* x     = (const float*)d_in[0];
  const int*   ei    = (const int*)d_in[1];
  const float* W     = (const float*)d_in[2];
  const float* a_src = (const float*)d_in[3];
  const float* a_dst = (const float*)d_in[4];
  float* out = (float*)d_out;
  char* ws = (char*)d_ws;

  float* h_f     = (float*)(ws + 0);          // 51,200,000 B
  float* s_src   = (float*)(ws + 51200000);   //  1,600,000 B
  float* s_dst   = (float*)(ws + 52800000);   //  1,600,000 B
  int*   count   = (int*)  (ws + 54400000);   //    200,000 B
  int*   row_ptr = (int*)  (ws + 54600000);   //    200,004 B
  int*   w_off   = (int*)  (ws + 54800064);   //    200,000 B
  int*   csr     = (int*)  (ws + 55000064);   //  3,200,000 B
  float* p_src   = (float*)(ws + 58200064);   //      8,192 B
  float* p_dst   = (float*)(ws + 58208256);   //      8,192 B

  hipMemsetAsync(count, 0, NN*sizeof(int), stream);
  k_pvec<<<8, 256, 0, stream>>>(W, a_src, a_dst, p_src, p_dst);
  k_gemm<<<((NN + TM - 1)/TM) * 2, 256, 0, stream>>>(x, W, h_f);
  k_scores<<<(NN + 15)/16, 256, 0, stream>>>(x, p_src, p_dst, s_src, s_dst);
  k_hist<<<EE/256, 256, 0, stream>>>(ei, count);
  k_scan<<<1, 1024, 0, stream>>>(count, row_ptr, w_off);
  k_scatter<<<EE/256, 256, 0, stream>>>(ei, w_off, csr);
  k_agg<<<(NN + 3)/4, 256, 0, stream>>>(row_ptr, csr, s_src, s_dst, h_f, out);
}

// Round 4
// 490.275 us; speedup vs baseline: 1.2954x; 1.2954x over previous
//
#include <hip/hip_runtime.h>
#include <stdint.h>

#define NN 50000
#define EE 800000
#define INF_ 256
#define OUTF 32
#define HH 8
#define NEG_SLOPE 0.2f
#define EPS_ 1e-8f
#define SCAN_B 196   // ceil(NN/256)

typedef unsigned short u16;
typedef unsigned int u32;

__device__ __forceinline__ float bflo(u32 w){ return __uint_as_float(w << 16); }
__device__ __forceinline__ float bfhi(u32 w){ return __uint_as_float(w & 0xFFFF0000u); }
__device__ __forceinline__ u16 f2bf(float f){
  u32 u = __float_as_uint(f);
  u += 0x7FFFu + ((u >> 16) & 1u);   // round-to-nearest-even
  return (u16)(u >> 16);
}

// ---------------- p-vectors: p[h,i] = sum_f W[h,i,f] * a[h,f] ----------------
__global__ void k_pvec(const float* __restrict__ W, const float* __restrict__ a_src,
                       const float* __restrict__ a_dst, float* __restrict__ p_src,
                       float* __restrict__ p_dst){
  int idx = blockIdx.x*blockDim.x + threadIdx.x;   // h*256 + i
  if (idx >= HH*INF_) return;
  int h = idx >> 8;
  const float* w = W + idx*OUTF;
  float ps = 0.f, pd = 0.f;
#pragma unroll
  for (int f = 0; f < OUTF; ++f){
    float wv = w[f];
    ps += wv * a_src[h*OUTF + f];
    pd += wv * a_dst[h*OUTF + f];
  }
  p_src[idx] = ps; p_dst[idx] = pd;
}

// ---------------- GEMM: h_bf[n, h*32+f] = bf16( sum_i x[n,i] W[h,i,f] ) ----------------
#define TM 128
#define TN 128
#define TK 32
#define LS 132   // padded LDS row stride (floats)

__global__ __launch_bounds__(256) void k_gemm(const float* __restrict__ x,
                                              const float* __restrict__ W,
                                              u16* __restrict__ h_out){
  __shared__ float As[TK*LS];
  __shared__ float Bs[TK*LS];
  int tid = threadIdx.x;
  int bx = blockIdx.x & 1;         // col tile
  int by = blockIdx.x >> 1;        // row tile
  int n0 = by*TM, c0 = bx*TN;
  int tx = tid & 15, ty = tid >> 4;
  float acc[8][8];
#pragma unroll
  for (int i=0;i<8;i++)
#pragma unroll
    for (int j=0;j<8;j++) acc[i][j]=0.f;

  int a_kg = tid & 7;        // k4-group
  int a_nd = tid >> 3;       // node 0..31 (+s*32)
  int b_fg = tid & 7;        // f4-group
  int b_h  = (tid >> 3) & 3; // head-local
  int b_kk = tid >> 5;       // kk 0..7 (+s*8)
  int h0 = c0 >> 5;

  for (int k0 = 0; k0 < INF_; k0 += TK){
#pragma unroll
    for (int s = 0; s < 4; ++s){
      int node = a_nd + s*32;
      int n = n0 + node;
      float4 u = make_float4(0.f,0.f,0.f,0.f);
      if (n < NN) u = *(const float4*)(x + n*INF_ + k0 + a_kg*4);
      int kb = a_kg*4;
      As[(kb+0)*LS + node] = u.x;
      As[(kb+1)*LS + node] = u.y;
      As[(kb+2)*LS + node] = u.z;
      As[(kb+3)*LS + node] = u.w;
    }
#pragma unroll
    for (int s = 0; s < 4; ++s){
      int kk = b_kk + s*8;
      float4 u = *(const float4*)(W + (h0 + b_h)*(INF_*OUTF) + (k0 + kk)*OUTF + b_fg*4);
      *(float4*)&Bs[kk*LS + b_h*32 + b_fg*4] = u;
    }
    __syncthreads();
#pragma unroll 8
    for (int kk = 0; kk < TK; ++kk){
      float4 A0 = *(const float4*)&As[kk*LS + ty*4];
      float4 A1 = *(const float4*)&As[kk*LS + 64 + ty*4];
      float4 B0 = *(const float4*)&Bs[kk*LS + tx*4];
      float4 B1 = *(const float4*)&Bs[kk*LS + 64 + tx*4];
      float av[8] = {A0.x,A0.y,A0.z,A0.w,A1.x,A1.y,A1.z,A1.w};
      float bv[8] = {B0.x,B0.y,B0.z,B0.w,B1.x,B1.y,B1.z,B1.w};
#pragma unroll
      for (int r=0;r<8;r++)
#pragma unroll
        for (int c=0;c<8;c++)
          acc[r][c] += av[r]*bv[c];
    }
    __syncthreads();
  }
#pragma unroll
  for (int r=0;r<8;r++){
    int node = (r<4) ? (ty*4 + r) : (64 + ty*4 + (r-4));
    int n = n0 + node;
    if (n >= NN) continue;
    ushort4 o0, o1;
    o0.x = f2bf(acc[r][0]); o0.y = f2bf(acc[r][1]); o0.z = f2bf(acc[r][2]); o0.w = f2bf(acc[r][3]);
    o1.x = f2bf(acc[r][4]); o1.y = f2bf(acc[r][5]); o1.z = f2bf(acc[r][6]); o1.w = f2bf(acc[r][7]);
    *(ushort4*)(h_out + n*INF_ + c0 + tx*4)      = o0;
    *(ushort4*)(h_out + n*INF_ + c0 + 64 + tx*4) = o1;
  }
}

// ---------------- scores: s_src[n,h] = x[n]·p_src[h], s_dst likewise ----------------
__global__ __launch_bounds__(256) void k_scores(const float* __restrict__ x,
    const float* __restrict__ p_src, const float* __restrict__ p_dst,
    float* __restrict__ s_src, float* __restrict__ s_dst){
  int tid = threadIdx.x;
  int n = blockIdx.x*16 + (tid >> 4);
  if (n >= NN) return;
  int slot = tid & 15;
  int h = slot & 7, isdst = slot >> 3;
  const float4* p4 = (const float4*)((isdst ? p_dst : p_src) + h*INF_);
  const float4* x4 = (const float4*)(x + n*INF_);
  float s = 0.f;
#pragma unroll 8
  for (int i = 0; i < 64; ++i){
    float4 a = x4[i], b = p4[i];
    s += a.x*b.x + a.y*b.y + a.z*b.z + a.w*b.w;
  }
  (isdst ? s_dst : s_src)[n*8 + h] = s;
}

// ---------------- CSR build: hist -> hierarchical scan -> scatter ----------------
__global__ void k_hist(const int* __restrict__ ei, int* __restrict__ count){
  int e = blockIdx.x*blockDim.x + threadIdx.x;
  if (e < EE) atomicAdd(&count[ei[EE + e]], 1);
}

__global__ void k_scan1(const int* __restrict__ count, int* __restrict__ bsum){
  __shared__ int lds[4];
  int t = threadIdx.x;
  int idx = blockIdx.x*256 + t;
  int v = (idx < NN) ? count[idx] : 0;
#pragma unroll
  for (int off = 32; off > 0; off >>= 1) v += __shfl_down(v, off, 64);
  if ((t & 63) == 0) lds[t >> 6] = v;
  __syncthreads();
  if (t == 0) bsum[blockIdx.x] = lds[0] + lds[1] + lds[2] + lds[3];
}

__global__ void k_scan2(const int* __restrict__ bsum, int* __restrict__ boff){
  __shared__ int lds[256];
  int t = threadIdx.x;
  int v = (t < SCAN_B) ? bsum[t] : 0;
  lds[t] = v;
  __syncthreads();
  for (int off = 1; off < 256; off <<= 1){
    int add = (t >= off) ? lds[t - off] : 0;
    __syncthreads();
    lds[t] += add;
    __syncthreads();
  }
  if (t < SCAN_B) boff[t] = lds[t] - v;   // exclusive prefix of block sums
}

__global__ void k_scan3(const int* __restrict__ count, const int* __restrict__ boff,
                        int* __restrict__ row_ptr, int* __restrict__ w_off){
  __shared__ int lds[256];
  int t = threadIdx.x;
  int idx = blockIdx.x*256 + t;
  int v = (idx < NN) ? count[idx] : 0;
  lds[t] = v;
  __syncthreads();
  for (int off = 1; off < 256; off <<= 1){
    int add = (t >= off) ? lds[t - off] : 0;
    __syncthreads();
    lds[t] += add;
    __syncthreads();
  }
  int excl = boff[blockIdx.x] + lds[t] - v;
  if (idx < NN){ row_ptr[idx] = excl; w_off[idx] = excl; }
  if (idx == 0) row_ptr[NN] = EE;     // total is statically known
}

__global__ void k_scatter(const int* __restrict__ ei, int* __restrict__ w_off,
                          int* __restrict__ csr){
  int e = blockIdx.x*blockDim.x + threadIdx.x;
  if (e < EE){
    int d = ei[EE + e];
    int pos = atomicAdd(&w_off[d], 1);
    csr[pos] = ei[e];              // src node id
  }
}

// ---------------- fused online-softmax aggregation: one wave per dst node ----------------
__global__ __launch_bounds__(256) void k_agg(const int* __restrict__ row_ptr,
    const int* __restrict__ csr, const float* __restrict__ s_src,
    const float* __restrict__ s_dst, const u16* __restrict__ h_bf,
    float* __restrict__ out){
  int lane = threadIdx.x & 63;
  int n = blockIdx.x*4 + (threadIdx.x >> 6);
  if (n >= NN) return;
  int h = lane >> 3, q = lane & 7;          // lane owns head h, f in [q*4, q*4+4)
  float sd = s_dst[n*8 + h];
  int beg = row_ptr[n], end = row_ptr[n+1];
  float m = -1e30f, l = 0.f;
  float a0=0.f, a1=0.f, a2=0.f, a3=0.f;
  for (int j = beg; j < end; ++j){
    int src = csr[j];
    float sc = s_src[src*8 + h] + sd;
    sc = sc > 0.f ? sc : NEG_SLOPE*sc;      // LeakyReLU
    float mn = fmaxf(m, sc);
    float scale = __expf(m - mn);           // exp(-huge)=0 handles first edge
    float p = __expf(sc - mn);
    m = mn;
    l = l*scale + p;
    uint2 hv = *(const uint2*)(h_bf + src*INF_ + h*32 + q*4);
    a0 = a0*scale + p*bflo(hv.x);
    a1 = a1*scale + p*bfhi(hv.x);
    a2 = a2*scale + p*bflo(hv.y);
    a3 = a3*scale + p*bfhi(hv.y);
  }
  float inv = 1.f/(l + EPS_);
  float4 o = make_float4(a0*inv, a1*inv, a2*inv, a3*inv);
  *(float4*)(out + n*INF_ + h*32 + q*4) = o;
}

// ---------------- launch ----------------
extern "C" void kernel_launch(void* const* d_in, const int* in_sizes, int n_in,
                              void* d_out, int out_size, void* d_ws, size_t ws_size,
                              hipStream_t stream){
  const float* x     = (const float*)d_in[0];
  const int*   ei    = (const int*)d_in[1];
  const float* W     = (const float*)d_in[2];
  const float* a_src = (const float*)d_in[3];
  const float* a_dst = (const float*)d_in[4];
  float* out = (float*)d_out;
  char* ws = (char*)d_ws;

  u16*   h_bf    = (u16*)  (ws + 0);          // 25,600,000 B
  float* s_src   = (float*)(ws + 25600000);   //  1,600,000 B
  float* s_dst   = (float*)(ws + 27200000);   //  1,600,000 B
  int*   count   = (int*)  (ws + 28800000);   //    200,000 B
  int*   row_ptr = (int*)  (ws + 29000000);   //    200,004 B
  int*   w_off   = (int*)  (ws + 29200064);   //    200,000 B
  int*   csr     = (int*)  (ws + 29400064);   //  3,200,000 B
  float* p_src   = (float*)(ws + 32600064);   //      8,192 B
  float* p_dst   = (float*)(ws + 32608256);   //      8,192 B
  int*   bsum    = (int*)  (ws + 32616448);   //        784 B
  int*   boff    = (int*)  (ws + 32617248);   //        784 B

  hipMemsetAsync(count, 0, NN*sizeof(int), stream);
  k_pvec<<<8, 256, 0, stream>>>(W, a_src, a_dst, p_src, p_dst);
  k_gemm<<<((NN + TM - 1)/TM) * 2, 256, 0, stream>>>(x, W, h_bf);
  k_scores<<<(NN + 15)/16, 256, 0, stream>>>(x, p_src, p_dst, s_src, s_dst);
  k_hist<<<EE/256, 256, 0, stream>>>(ei, count);
  k_scan1<<<SCAN_B, 256, 0, stream>>>(count, bsum);
  k_scan2<<<1, 256, 0, stream>>>(bsum, boff);
  k_scan3<<<SCAN_B, 256, 0, stream>>>(count, boff, row_ptr, w_off);
  k_scatter<<<EE/256, 256, 0, stream>>>(ei, w_off, csr);
  k_agg<<<(NN + 3)/4, 256, 0, stream>>>(row_ptr, csr, s_src, s_dst, h_bf, out);
}

// Round 5
// 434.869 us; speedup vs baseline: 1.4605x; 1.1274x over previous
//
#include <hip/hip_runtime.h>
#include <stdint.h>

#define NN 50000
#define EE 800000
#define INF_ 256
#define OUTF 32
#define HH 8
#define NEG_SLOPE 0.2f
#define EPS_ 1e-8f
#define SCAN_B 196   // ceil(NN/256)

typedef unsigned short u16;
typedef unsigned int u32;

__device__ __forceinline__ float bflo(u32 w){ return __uint_as_float(w << 16); }
__device__ __forceinline__ float bfhi(u32 w){ return __uint_as_float(w & 0xFFFF0000u); }
__device__ __forceinline__ u16 f2bf(float f){
  u32 u = __float_as_uint(f);
  u += 0x7FFFu + ((u >> 16) & 1u);   // round-to-nearest-even
  return (u16)(u >> 16);
}

// ------- GEMM + fused scores:
//   h_bf[n, h*32+f] = bf16( sum_i x[n,i] W[h,i,f] )
//   s_src[n,h] = sum_f h[n,h,f]*a_src[h,f]   (fp32, from unrounded acc)
#define TM 128
#define TN 128
#define TK 32
#define LS 132   // padded LDS row stride (floats)

__global__ __launch_bounds__(256) void k_gemm(const float* __restrict__ x,
                                              const float* __restrict__ W,
                                              const float* __restrict__ a_src,
                                              const float* __restrict__ a_dst,
                                              u16* __restrict__ h_out,
                                              float* __restrict__ s_src,
                                              float* __restrict__ s_dst){
  __shared__ float As[TK*LS];
  __shared__ float Bs[TK*LS];
  __shared__ float s_part[TM*8];   // [row][head_local(4)][src/dst(2)]
  int tid = threadIdx.x;
  int bx = blockIdx.x & 1;         // col tile -> heads h0..h0+3
  int by = blockIdx.x >> 1;        // row tile
  int n0 = by*TM, c0 = bx*TN;
  int tx = tid & 15, ty = tid >> 4;
  float acc[8][8];
#pragma unroll
  for (int i=0;i<8;i++)
#pragma unroll
    for (int j=0;j<8;j++) acc[i][j]=0.f;

  for (int i = tid; i < TM*8; i += 256) s_part[i] = 0.f;

  int a_kg = tid & 7;        // k4-group
  int a_nd = tid >> 3;       // node 0..31 (+s*32)
  int b_fg = tid & 7;        // f4-group
  int b_h  = (tid >> 3) & 3; // head-local
  int b_kk = tid >> 5;       // kk 0..7 (+s*8)
  int h0 = c0 >> 5;

  for (int k0 = 0; k0 < INF_; k0 += TK){
#pragma unroll
    for (int s = 0; s < 4; ++s){
      int node = a_nd + s*32;
      int n = n0 + node;
      float4 u = make_float4(0.f,0.f,0.f,0.f);
      if (n < NN) u = *(const float4*)(x + n*INF_ + k0 + a_kg*4);
      int kb = a_kg*4;
      As[(kb+0)*LS + node] = u.x;
      As[(kb+1)*LS + node] = u.y;
      As[(kb+2)*LS + node] = u.z;
      As[(kb+3)*LS + node] = u.w;
    }
#pragma unroll
    for (int s = 0; s < 4; ++s){
      int kk = b_kk + s*8;
      float4 u = *(const float4*)(W + (h0 + b_h)*(INF_*OUTF) + (k0 + kk)*OUTF + b_fg*4);
      *(float4*)&Bs[kk*LS + b_h*32 + b_fg*4] = u;
    }
    __syncthreads();
#pragma unroll 8
    for (int kk = 0; kk < TK; ++kk){
      float4 A0 = *(const float4*)&As[kk*LS + ty*4];
      float4 A1 = *(const float4*)&As[kk*LS + 64 + ty*4];
      float4 B0 = *(const float4*)&Bs[kk*LS + tx*4];
      float4 B1 = *(const float4*)&Bs[kk*LS + 64 + tx*4];
      float av[8] = {A0.x,A0.y,A0.z,A0.w,A1.x,A1.y,A1.z,A1.w};
      float bv[8] = {B0.x,B0.y,B0.z,B0.w,B1.x,B1.y,B1.z,B1.w};
#pragma unroll
      for (int r=0;r<8;r++)
#pragma unroll
        for (int c=0;c<8;c++)
          acc[r][c] += av[r]*bv[c];
    }
    __syncthreads();
  }

  // ---- h output (bf16) ----
#pragma unroll
  for (int r=0;r<8;r++){
    int node = (r<4) ? (ty*4 + r) : (64 + ty*4 + (r-4));
    int n = n0 + node;
    if (n >= NN) continue;
    ushort4 o0, o1;
    o0.x = f2bf(acc[r][0]); o0.y = f2bf(acc[r][1]); o0.z = f2bf(acc[r][2]); o0.w = f2bf(acc[r][3]);
    o1.x = f2bf(acc[r][4]); o1.y = f2bf(acc[r][5]); o1.z = f2bf(acc[r][6]); o1.w = f2bf(acc[r][7]);
    *(ushort4*)(h_out + n*INF_ + c0 + tx*4)      = o0;
    *(ushort4*)(h_out + n*INF_ + c0 + 64 + tx*4) = o1;
  }

  // ---- fused scores: dot acc fragments with a_src/a_dst ----
  int f0  = (tx*4) & 31;     // f offset within head (cols are 4-aligned in 32-wide heads)
  int hl0 = tx >> 3;         // head_local of cols tx*4..+3   (0 or 1)
  int hl1 = 2 + hl0;         // head_local of cols 64+tx*4..+3
  float4 as0 = *(const float4*)(a_src + (h0+hl0)*OUTF + f0);
  float4 ad0 = *(const float4*)(a_dst + (h0+hl0)*OUTF + f0);
  float4 as1 = *(const float4*)(a_src + (h0+hl1)*OUTF + f0);
  float4 ad1 = *(const float4*)(a_dst + (h0+hl1)*OUTF + f0);
#pragma unroll
  for (int r=0;r<8;r++){
    int node = (r<4) ? (ty*4 + r) : (64 + ty*4 + (r-4));
    float ps0 = acc[r][0]*as0.x + acc[r][1]*as0.y + acc[r][2]*as0.z + acc[r][3]*as0.w;
    float pd0 = acc[r][0]*ad0.x + acc[r][1]*ad0.y + acc[r][2]*ad0.z + acc[r][3]*ad0.w;
    float ps1 = acc[r][4]*as1.x + acc[r][5]*as1.y + acc[r][6]*as1.z + acc[r][7]*as1.w;
    float pd1 = acc[r][4]*ad1.x + acc[r][5]*ad1.y + acc[r][6]*ad1.z + acc[r][7]*ad1.w;
    atomicAdd(&s_part[node*8 + hl0*2 + 0], ps0);
    atomicAdd(&s_part[node*8 + hl0*2 + 1], pd0);
    atomicAdd(&s_part[node*8 + hl1*2 + 0], ps1);
    atomicAdd(&s_part[node*8 + hl1*2 + 1], pd1);
  }
  __syncthreads();
  for (int i = tid; i < TM*4; i += 256){
    int node = i >> 2, hl = i & 3;
    int n = n0 + node;
    if (n < NN){
      s_src[n*8 + h0 + hl] = s_part[node*8 + hl*2 + 0];
      s_dst[n*8 + h0 + hl] = s_part[node*8 + hl*2 + 1];
    }
  }
}

// ---------------- CSR build: hist -> hierarchical scan -> scatter ----------------
__global__ void k_hist(const int* __restrict__ ei, int* __restrict__ count){
  int e = blockIdx.x*blockDim.x + threadIdx.x;
  if (e < EE) atomicAdd(&count[ei[EE + e]], 1);
}

__global__ void k_scan1(const int* __restrict__ count, int* __restrict__ bsum){
  __shared__ int lds[4];
  int t = threadIdx.x;
  int idx = blockIdx.x*256 + t;
  int v = (idx < NN) ? count[idx] : 0;
#pragma unroll
  for (int off = 32; off > 0; off >>= 1) v += __shfl_down(v, off, 64);
  if ((t & 63) == 0) lds[t >> 6] = v;
  __syncthreads();
  if (t == 0) bsum[blockIdx.x] = lds[0] + lds[1] + lds[2] + lds[3];
}

__global__ void k_scan2(const int* __restrict__ bsum, int* __restrict__ boff){
  __shared__ int lds[256];
  int t = threadIdx.x;
  int v = (t < SCAN_B) ? bsum[t] : 0;
  lds[t] = v;
  __syncthreads();
  for (int off = 1; off < 256; off <<= 1){
    int add = (t >= off) ? lds[t - off] : 0;
    __syncthreads();
    lds[t] += add;
    __syncthreads();
  }
  if (t < SCAN_B) boff[t] = lds[t] - v;   // exclusive prefix of block sums
}

__global__ void k_scan3(const int* __restrict__ count, const int* __restrict__ boff,
                        int* __restrict__ row_ptr, int* __restrict__ w_off){
  __shared__ int lds[256];
  int t = threadIdx.x;
  int idx = blockIdx.x*256 + t;
  int v = (idx < NN) ? count[idx] : 0;
  lds[t] = v;
  __syncthreads();
  for (int off = 1; off < 256; off <<= 1){
    int add = (t >= off) ? lds[t - off] : 0;
    __syncthreads();
    lds[t] += add;
    __syncthreads();
  }
  int excl = boff[blockIdx.x] + lds[t] - v;
  if (idx < NN){ row_ptr[idx] = excl; w_off[idx] = excl; }
  if (idx == 0) row_ptr[NN] = EE;     // total is statically known
}

__global__ void k_scatter(const int* __restrict__ ei, int* __restrict__ w_off,
                          int* __restrict__ csr){
  int e = blockIdx.x*blockDim.x + threadIdx.x;
  if (e < EE){
    int d = ei[EE + e];
    int pos = atomicAdd(&w_off[d], 1);
    csr[pos] = ei[e];              // src node id
  }
}

// ---------------- fused online-softmax aggregation: one wave per dst node ----------------
__global__ __launch_bounds__(256) void k_agg(const int* __restrict__ row_ptr,
    const int* __restrict__ csr, const float* __restrict__ s_src,
    const float* __restrict__ s_dst, const u16* __restrict__ h_bf,
    float* __restrict__ out){
  int lane = threadIdx.x & 63;
  int n = blockIdx.x*4 + (threadIdx.x >> 6);
  if (n >= NN) return;
  int h = lane >> 3, q = lane & 7;          // lane owns head h, f in [q*4, q*4+4)
  float sd = s_dst[n*8 + h];
  int beg = row_ptr[n], end = row_ptr[n+1];
  float m = -1e30f, l = 0.f;
  float a0=0.f, a1=0.f, a2=0.f, a3=0.f;
  for (int j = beg; j < end; ++j){
    int src = csr[j];
    float sc = s_src[src*8 + h] + sd;
    sc = sc > 0.f ? sc : NEG_SLOPE*sc;      // LeakyReLU
    float mn = fmaxf(m, sc);
    float scale = __expf(m - mn);           // exp(-huge)=0 handles first edge
    float p = __expf(sc - mn);
    m = mn;
    l = l*scale + p;
    uint2 hv = *(const uint2*)(h_bf + src*INF_ + h*32 + q*4);
    a0 = a0*scale + p*bflo(hv.x);
    a1 = a1*scale + p*bfhi(hv.x);
    a2 = a2*scale + p*bflo(hv.y);
    a3 = a3*scale + p*bfhi(hv.y);
  }
  float inv = 1.f/(l + EPS_);
  float4 o = make_float4(a0*inv, a1*inv, a2*inv, a3*inv);
  *(float4*)(out + n*INF_ + h*32 + q*4) = o;
}

// ---------------- launch ----------------
extern "C" void kernel_launch(void* const* d_in, const int* in_sizes, int n_in,
                              void* d_out, int out_size, void* d_ws, size_t ws_size,
                              hipStream_t stream){
  const float* x     = (const float*)d_in[0];
  const int*   ei    = (const int*)d_in[1];
  const float* W     = (const float*)d_in[2];
  const float* a_src = (const float*)d_in[3];
  const float* a_dst = (const float*)d_in[4];
  float* out = (float*)d_out;
  char* ws = (char*)d_ws;

  u16*   h_bf    = (u16*)  (ws + 0);          // 25,600,000 B
  float* s_src   = (float*)(ws + 25600000);   //  1,600,000 B
  float* s_dst   = (float*)(ws + 27200000);   //  1,600,000 B
  int*   count   = (int*)  (ws + 28800000);   //    200,000 B
  int*   row_ptr = (int*)  (ws + 29000000);   //    200,004 B
  int*   w_off   = (int*)  (ws + 29200064);   //    200,000 B
  int*   csr     = (int*)  (ws + 29400064);   //  3,200,000 B
  int*   bsum    = (int*)  (ws + 32600064);   //        784 B
  int*   boff    = (int*)  (ws + 32600864);   //        784 B

  hipMemsetAsync(count, 0, NN*sizeof(int), stream);
  k_gemm<<<((NN + TM - 1)/TM) * 2, 256, 0, stream>>>(x, W, a_src, a_dst, h_bf, s_src, s_dst);
  k_hist<<<EE/256, 256, 0, stream>>>(ei, count);
  k_scan1<<<SCAN_B, 256, 0, stream>>>(count, bsum);
  k_scan2<<<1, 256, 0, stream>>>(bsum, boff);
  k_scan3<<<SCAN_B, 256, 0, stream>>>(count, boff, row_ptr, w_off);
  k_scatter<<<EE/256, 256, 0, stream>>>(ei, w_off, csr);
  k_agg<<<(NN + 3)/4, 256, 0, stream>>>(row_ptr, csr, s_src, s_dst, h_bf, out);
}